// Round 16
// baseline (57.808 us; speedup 1.0000x reference)
//
#include <hip/hip_runtime.h>

#define B     128
#define NE    14951
#define NEP   14976     // 117*128 = 936*16, padded entity count
#define NR    1345
#define D     200
#define NL    116
#define NLP   120       // padded literal count (15 bf16x8 slots)
#define D2    100
#define EB    4
#define LOG2E 1.4426950408889634f

typedef __attribute__((ext_vector_type(8))) short bf16x8;
typedef __attribute__((ext_vector_type(4))) float f32x4;

// ---- ws layout (floats), fast path ----
#define OFF_ET   0                            // uint4[28][NEP] : E bf16x8, slot s = d 8s..8s+7 (d>=200 zero)
#define OFF_WA   (OFF_ET + 28*NEP*4)          // uint4[28][128] : w  bf16x8, same k-chunking
#define OFF_LT   (OFF_WA + 28*128*4)          // uint4[15][NEP] : lit bf16x8, slot s = l 8s..8s+7 (l>=116 zero)
#define OFF_SL   (OFF_LT + 15*NEP*4)          // float[128][NEP]: score_l
#define OFF_UB   (OFF_SL + 128*NEP)           // [128][120] fp32: u = -2*q*a   (pad 0)
#define OFF_FB   (OFF_UB + 128*NLP)           // [128][120] fp32: w' = wnf*exp2(q*a^2) (pad 0)
#define OFF_NQ   (OFF_FB + 128*NLP)           // [120] fp32     : q (pad -1)
#define WS_FLOATS (OFF_NQ + 128)
#define WS_NEEDED ((size_t)WS_FLOATS * 4)

__device__ __forceinline__ unsigned bf16rne(float f) {
    unsigned u = __float_as_uint(f);
    u += 0x7FFFu + ((u >> 16) & 1u);
    return u >> 16;
}
#define BF2F_LO(u) __uint_as_float((u) << 16)
#define BF2F_HI(u) __uint_as_float((u) & 0xffff0000u)

// ---------------- fused prep: 3 roles by blockIdx range ----------------
// role A: E -> ET bf16x8 [28][NEP]  : 234 * 7 = 1638 blocks
// role B: lit -> LT bf16x8 [15][NEP]: 234 * 4 = 936 blocks
// role C: per-batch prep + WA pack  : 64 blocks (2 b each)
#define NB_A 1638
#define NB_B 936
#define NB_C 64

__global__ __launch_bounds__(256) void prep_all(
    const int* __restrict__ e1_idx, const int* __restrict__ r_idx,
    const float* __restrict__ E, const float* __restrict__ R,
    const float* __restrict__ nf, const float* __restrict__ lit,
    const float* __restrict__ c, const float* __restrict__ var,
    float* __restrict__ ws)
{
    __shared__ float lwb[2][224];
    const int bid = blockIdx.x;
    const int t   = threadIdx.x;

    if (bid < NB_A) {                       // ---- E -> bf16x8 [28][NEP] ----
        const int ebk = bid % 234;
        const int cq  = (bid / 234) * 4 + (t >> 6);   // 0..27
        const int e   = ebk * 64 + (t & 63);
        uint4 o = make_uint4(0u, 0u, 0u, 0u);
        if (e < NE && cq < 25) {            // d = 8cq..8cq+7 < 200
            float4 a = *(const float4*)(E + e*D + 8*cq);
            float4 b = *(const float4*)(E + e*D + 8*cq + 4);
            o.x = bf16rne(a.x) | (bf16rne(a.y) << 16);
            o.y = bf16rne(a.z) | (bf16rne(a.w) << 16);
            o.z = bf16rne(b.x) | (bf16rne(b.y) << 16);
            o.w = bf16rne(b.z) | (bf16rne(b.w) << 16);
        }
        ((uint4*)(ws + OFF_ET))[cq*NEP + e] = o;
    } else if (bid < NB_A + NB_B) {         // ---- lit -> bf16x8 [15][NEP] ----
        const int idx = bid - NB_A;
        const int ebk = idx % 234;
        const int s   = (idx / 234) * 4 + (t >> 6);   // 0..15
        const int e   = ebk * 64 + (t & 63);
        if (s >= 15) return;
        uint4 o = make_uint4(0u, 0u, 0u, 0u);
        if (e < NE) {
            float4 a = *(const float4*)(lit + e*NL + 8*s);
            o.x = bf16rne(a.x) | (bf16rne(a.y) << 16);
            o.y = bf16rne(a.z) | (bf16rne(a.w) << 16);
            if (s < 14) {
                float4 b = *(const float4*)(lit + e*NL + 8*s + 4);
                o.z = bf16rne(b.x) | (bf16rne(b.y) << 16);
                o.w = bf16rne(b.z) | (bf16rne(b.w) << 16);
            }
        }
        ((uint4*)(ws + OFF_LT))[s*NEP + e] = o;
    } else {                                // ---- per-batch prep + WA pack ----
        const int cb  = bid - NB_A - NB_B;  // 0..63
        const int sub = t >> 7;             // 0..1
        const int b   = cb*2 + sub;
        const int tt  = t & 127;
        const int e1 = e1_idx[b];
        const int r  = r_idx[b];
        if (tt < D2) {
            float e1r = E[e1*D + tt],      e1i = E[e1*D + D2 + tt];
            float rr  = R[r*D + tt],       ri  = R[r*D + D2 + tt];
            lwb[sub][tt]      = e1r*rr - e1i*ri;
            lwb[sub][D2 + tt] = e1r*ri + e1i*rr;
        }
        if (tt >= 100 && tt < 124) lwb[sub][100 + tt] = 0.f;   // d = 200..223
        if (tt < NLP) {
            float uu = 0.f, ff = 0.f, qq = -1.0f;
            if (tt < NL) {
                float a = lit[e1*NL + tt] - c[tt];
                qq = -LOG2E / var[tt];
                uu = -2.0f * qq * a;
                ff = nf[r*NL + tt] * __builtin_amdgcn_exp2f(qq * a * a);
            }
            (ws + OFF_UB)[b*NLP + tt] = uu;
            (ws + OFF_FB)[b*NLP + tt] = ff;
            if (b == 0) (ws + OFF_NQ)[tt] = qq;
        }
        __syncthreads();
        if (tt < 28) {
            const float* w8 = &lwb[sub][8*tt];
            uint4 o;
            o.x = bf16rne(w8[0]) | (bf16rne(w8[1]) << 16);
            o.y = bf16rne(w8[2]) | (bf16rne(w8[3]) << 16);
            o.z = bf16rne(w8[4]) | (bf16rne(w8[5]) << 16);
            o.w = bf16rne(w8[6]) | (bf16rne(w8[7]) << 16);
            ((uint4*)(ws + OFF_WA))[tt*128 + b] = o;
        }
    }
}

// ---------------- gemm: SL[b][e] = sum_d w[b][d]*E[e][d], bf16 MFMA ----------------
// (unchanged from R13 — verified passing)

__global__ __launch_bounds__(256) void gemm_kernel(
    const uint4* __restrict__ et, const uint4* __restrict__ wa,
    float* __restrict__ sl)
{
    const int gw = blockIdx.x * 4 + (threadIdx.x >> 6);  // 0..7487
    const int l  = threadIdx.x & 63;
    const int mb = gw / 936;            // 0..7   (b-tile)
    const int nb = gw - mb*936;         // 0..935 (e-tile)
    const int lane16 = l & 15;
    const int grp    = l >> 4;
    const int e = nb*16 + lane16;

    f32x4 acc = {0.f, 0.f, 0.f, 0.f};
#pragma unroll
    for (int kc = 0; kc < 7; ++kc) {
        const int s = kc*4 + grp;
        bf16x8 a = *(const bf16x8*)(wa + s*128 + mb*16 + lane16);
        bf16x8 b = *(const bf16x8*)(et + s*NEP + e);
        acc = __builtin_amdgcn_mfma_f32_16x16x32_bf16(a, b, acc, 0, 0, 0);
    }
    const int brow = mb*16 + grp*4;
#pragma unroll
    for (int r = 0; r < 4; ++r)
        sl[(brow + r)*NEP + e] = acc[r];
}

// ---------------- score_n: lane = entity; bf16x8 L slots; scalar batch operands ----------------

#define SN_STEP8(lv, ss) do {                                             \
    float L0 = BF2F_LO((lv).x), L1 = BF2F_HI((lv).x);                     \
    float L2 = BF2F_LO((lv).y), L3 = BF2F_HI((lv).y);                     \
    float L4 = BF2F_LO((lv).z), L5 = BF2F_HI((lv).z);                     \
    float L6 = BF2F_LO((lv).w), L7 = BF2F_HI((lv).w);                     \
    float4 qa = *(const float4*)(nq + 8*(ss));                            \
    float4 qb = *(const float4*)(nq + 8*(ss) + 4);                        \
    float g0 = (qa.x*L0)*L0, g1 = (qa.y*L1)*L1;                           \
    float g2 = (qa.z*L2)*L2, g3 = (qa.w*L3)*L3;                           \
    float g4 = (qb.x*L4)*L4, g5 = (qb.y*L5)*L5;                           \
    float g6 = (qb.z*L6)*L6, g7 = (qb.w*L7)*L7;                           \
    _Pragma("unroll")                                                     \
    for (int j = 0; j < EB; ++j) {                                        \
        float4 ua = *(const float4*)(ub + (b0+j)*NLP + 8*(ss));           \
        float4 uc = *(const float4*)(ub + (b0+j)*NLP + 8*(ss) + 4);       \
        float4 fa = *(const float4*)(fb + (b0+j)*NLP + 8*(ss));           \
        float4 fc = *(const float4*)(fb + (b0+j)*NLP + 8*(ss) + 4);       \
        acc[j] = fmaf(fa.x, __builtin_amdgcn_exp2f(fmaf(ua.x, L0, g0)), acc[j]); \
        acc[j] = fmaf(fa.y, __builtin_amdgcn_exp2f(fmaf(ua.y, L1, g1)), acc[j]); \
        acc[j] = fmaf(fa.z, __builtin_amdgcn_exp2f(fmaf(ua.z, L2, g2)), acc[j]); \
        acc[j] = fmaf(fa.w, __builtin_amdgcn_exp2f(fmaf(ua.w, L3, g3)), acc[j]); \
        acc[j] = fmaf(fc.x, __builtin_amdgcn_exp2f(fmaf(uc.x, L4, g4)), acc[j]); \
        acc[j] = fmaf(fc.y, __builtin_amdgcn_exp2f(fmaf(uc.y, L5, g5)), acc[j]); \
        acc[j] = fmaf(fc.z, __builtin_amdgcn_exp2f(fmaf(uc.z, L6, g6)), acc[j]); \
        acc[j] = fmaf(fc.w, __builtin_amdgcn_exp2f(fmaf(uc.w, L7, g7)), acc[j]); \
    }                                                                     \
} while (0)

__global__ __launch_bounds__(256) void score_kernel(
    const float* __restrict__ lt, const float* __restrict__ sl,
    const float* __restrict__ ub, const float* __restrict__ fb,
    const float* __restrict__ nq, float* __restrict__ out)
{
    // grid = 1888 = 59 eblk2(256 e) * 32 bblk; both block halves share b0
    // (b0 derived from blockIdx ONLY -> scalar operand path preserved)
    const int lid   = blockIdx.x;
    const int p     = (lid & 7) * 236 + (lid >> 3);  // XCD-contiguous, bijective (1888 = 8*236)
    const int bblk  = p & 31;           // 0..31
    const int eblk2 = p >> 5;           // 0..58
    const int e     = eblk2 * 256 + threadIdx.x;
    const int ec    = min(e, NEP - 1);  // tail clamp (tables sized NEP)
    const int b0    = bblk * EB;

    // ---- acc init from MFMA score_l ----
    float acc[EB];
#pragma unroll
    for (int j = 0; j < EB; ++j) acc[j] = sl[(b0+j)*NEP + ec];

    const uint4* L8 = (const uint4*)lt;

    // ---- score_n: 15 bf16x8 slots, 2-deep rolling prefetch ----
    {
        uint4 v0 = L8[0*NEP + ec];
        uint4 v1 = L8[1*NEP + ec];
        for (int s0 = 0; s0 < 12; s0 += 2) {
            SN_STEP8(v0, s0);     v0 = L8[(s0 + 2)*NEP + ec];
            SN_STEP8(v1, s0 + 1); v1 = L8[(s0 + 3)*NEP + ec];
        }
        // v0 = slot 12, v1 = slot 13
        SN_STEP8(v0, 12); v0 = L8[14*NEP + ec];
        SN_STEP8(v1, 13);
        SN_STEP8(v0, 14);
    }

    // ---- sigmoid + coalesced store ----
    if (e < NE) {
#pragma unroll
        for (int j = 0; j < EB; ++j) {
            float s = __builtin_amdgcn_rcpf(1.0f + __builtin_amdgcn_exp2f(acc[j] * -LOG2E));
            out[(b0+j)*NE + e] = s;
        }
    }
}

// ---------------- legacy fallback (ws too small) ----------------

#define ET  4
#define OFF_W   0
#define OFF_A   25600
#define OFF_WNF 40448
#define OFF_NQL 55296

__global__ __launch_bounds__(128) void prep_kernel_legacy(
    const int* __restrict__ e1_idx, const int* __restrict__ r_idx,
    const float* __restrict__ E, const float* __restrict__ R,
    const float* __restrict__ nf, const float* __restrict__ lit,
    const float* __restrict__ c, const float* __restrict__ var,
    float* __restrict__ ws)
{
    const int b = blockIdx.x;
    const int t = threadIdx.x;
    const int e1 = e1_idx[b];
    const int r  = r_idx[b];
    if (t < D2) {
        float e1r = E[e1*D + t], e1i = E[e1*D + D2 + t];
        float rr  = R[r*D + t],  ri  = R[r*D + D2 + t];
        ws[OFF_W + (t >> 2)*512        + (b << 2) + (t & 3)] = e1r*rr - e1i*ri;
        ws[OFF_W + ((t >> 2) + 25)*512 + (b << 2) + (t & 3)] = e1r*ri + e1i*rr;
    }
    if (t < NL) {
        ws[OFF_A   + (t >> 2)*512 + (b << 2) + (t & 3)] = lit[e1*NL + t] - c[t];
        ws[OFF_WNF + (t >> 2)*512 + (b << 2) + (t & 3)] = nf[r*NL + t];
        if (b == 0) ws[OFF_NQL + t] = -LOG2E / var[t];
    }
}

__global__ __launch_bounds__(128) void main_kernel_legacy(
    const float* __restrict__ E, const float* __restrict__ lit,
    const float* __restrict__ ws, float* __restrict__ out)
{
    const int b  = threadIdx.x;
    const int e0 = blockIdx.x * ET;
    const float4* w4   = (const float4*)(ws + OFF_W);
    const float4* a4   = (const float4*)(ws + OFF_A);
    const float4* wnf4 = (const float4*)(ws + OFF_WNF);
    const float*  nqv  = ws + OFF_NQL;
    int eidx[ET];
#pragma unroll
    for (int j = 0; j < ET; ++j) eidx[j] = min(e0 + j, NE - 1);
    float acc[ET];
#pragma unroll
    for (int j = 0; j < ET; ++j) acc[j] = 0.0f;
    for (int dc = 0; dc < D; dc += 4) {
        float4 wv = w4[(dc >> 2)*B + b];
#pragma unroll
        for (int j = 0; j < ET; ++j) {
            float4 ev = *(const float4*)(E + eidx[j]*D + dc);
            acc[j] = fmaf(wv.x, ev.x, acc[j]);
            acc[j] = fmaf(wv.y, ev.y, acc[j]);
            acc[j] = fmaf(wv.z, ev.z, acc[j]);
            acc[j] = fmaf(wv.w, ev.w, acc[j]);
        }
    }
    for (int lc = 0; lc < NL; lc += 4) {
        float4 av = a4[(lc >> 2)*B + b];
        float4 wv = wnf4[(lc >> 2)*B + b];
        float4 q  = *(const float4*)(nqv + lc);
#pragma unroll
        for (int j = 0; j < ET; ++j) {
            float4 lv = *(const float4*)(lit + eidx[j]*NL + lc);
            float t0 = av.x - lv.x, t1 = av.y - lv.y, t2 = av.z - lv.z, t3 = av.w - lv.w;
            acc[j] += wv.x * __builtin_amdgcn_exp2f(t0*t0*q.x);
            acc[j] += wv.y * __builtin_amdgcn_exp2f(t1*t1*q.y);
            acc[j] += wv.z * __builtin_amdgcn_exp2f(t2*t2*q.z);
            acc[j] += wv.w * __builtin_amdgcn_exp2f(t3*t3*q.w);
        }
    }
#pragma unroll
    for (int j = 0; j < ET; ++j) {
        float s = 1.0f / (1.0f + __builtin_amdgcn_exp2f(acc[j] * -LOG2E));
        int e = e0 + j;
        if (e < NE) out[b*NE + e] = s;
    }
}

// ---------------- launch ----------------

extern "C" void kernel_launch(void* const* d_in, const int* in_sizes, int n_in,
                              void* d_out, int out_size, void* d_ws, size_t ws_size,
                              hipStream_t stream) {
    const int*   e1_idx = (const int*)d_in[0];
    const int*   r_idx  = (const int*)d_in[1];
    const float* E      = (const float*)d_in[2];
    const float* R      = (const float*)d_in[3];
    const float* nf     = (const float*)d_in[4];
    const float* lit    = (const float*)d_in[5];
    const float* c      = (const float*)d_in[6];
    const float* var    = (const float*)d_in[7];
    float* out = (float*)d_out;
    float* ws  = (float*)d_ws;

    if (ws_size >= WS_NEEDED) {
        prep_all<<<NB_A + NB_B + NB_C, 256, 0, stream>>>(
            e1_idx, r_idx, E, R, nf, lit, c, var, ws);
        gemm_kernel<<<1872, 256, 0, stream>>>(
            (const uint4*)(ws + OFF_ET), (const uint4*)(ws + OFF_WA), ws + OFF_SL);
        score_kernel<<<1888, 256, 0, stream>>>(
            ws + OFF_LT, ws + OFF_SL, ws + OFF_UB, ws + OFF_FB, ws + OFF_NQ, out);
    } else {
        prep_kernel_legacy<<<B, 128, 0, stream>>>(e1_idx, r_idx, E, R, nf, lit, c, var, ws);
        main_kernel_legacy<<<(NE + ET - 1)/ET, B, 0, stream>>>(E, lit, ws, out);
    }
}

// Round 17
// 56.584 us; speedup vs baseline: 1.0216x; 1.0216x over previous
//
#include <hip/hip_runtime.h>

#define B     128
#define NE    14951
#define NEP   14976     // 117*128 = 936*16, padded entity count
#define NR    1345
#define D     200
#define NL    116
#define D2    100
#define EB    4
#define LOG2E 1.4426950408889634f

typedef __attribute__((ext_vector_type(8))) short bf16x8;
typedef __attribute__((ext_vector_type(4))) float f32x4;

// ---- ws layout (floats), fast path ----
#define OFF_ET   0                            // uint4[28][NEP] : E bf16x8, slot s = d 8s..8s+7 (d>=200 zero)
#define OFF_WA   (OFF_ET + 28*NEP*4)          // uint4[28][128] : w  bf16x8, same k-chunking
#define OFF_LT   (OFF_WA + 28*128*4)          // uint2[29][NEP] : lit bf16x4
#define OFF_SL   (OFF_LT + 29*NEP*2)          // float[128][NEP]: score_l
#define OFF_UF   (OFF_SL + 128*NEP)           // float[128][29][8]: {u0..3,f0..3} interleaved (32B units)
#define OFF_NQ   (OFF_UF + 128*232)           // [116] fp32     : q
#define WS_FLOATS (OFF_NQ + 128)
#define WS_NEEDED ((size_t)WS_FLOATS * 4)

__device__ __forceinline__ unsigned bf16rne(float f) {
    unsigned u = __float_as_uint(f);
    u += 0x7FFFu + ((u >> 16) & 1u);
    return u >> 16;
}
#define BF2F_LO(u) __uint_as_float((u) << 16)
#define BF2F_HI(u) __uint_as_float((u) & 0xffff0000u)

// ---------------- fused prep: 3 roles by blockIdx range ----------------
// role A: E -> ET bf16x8 [28][NEP]  : 234 * 7 = 1638 blocks
// role B: lit -> LT bf16x4 [29][NEP]: 234 * 8 = 1872 blocks
// role C: per-batch prep + WA pack  : 64 blocks (2 b each)
#define NB_A 1638
#define NB_B 1872
#define NB_C 64

__global__ __launch_bounds__(256) void prep_all(
    const int* __restrict__ e1_idx, const int* __restrict__ r_idx,
    const float* __restrict__ E, const float* __restrict__ R,
    const float* __restrict__ nf, const float* __restrict__ lit,
    const float* __restrict__ c, const float* __restrict__ var,
    float* __restrict__ ws)
{
    __shared__ float lwb[2][224];
    const int bid = blockIdx.x;
    const int t   = threadIdx.x;

    if (bid < NB_A) {                       // ---- E -> bf16x8 [28][NEP] ----
        const int ebk = bid % 234;
        const int cq  = (bid / 234) * 4 + (t >> 6);   // 0..27
        const int e   = ebk * 64 + (t & 63);
        uint4 o = make_uint4(0u, 0u, 0u, 0u);
        if (e < NE && cq < 25) {            // d = 8cq..8cq+7 < 200
            float4 a = *(const float4*)(E + e*D + 8*cq);
            float4 b = *(const float4*)(E + e*D + 8*cq + 4);
            o.x = bf16rne(a.x) | (bf16rne(a.y) << 16);
            o.y = bf16rne(a.z) | (bf16rne(a.w) << 16);
            o.z = bf16rne(b.x) | (bf16rne(b.y) << 16);
            o.w = bf16rne(b.z) | (bf16rne(b.w) << 16);
        }
        ((uint4*)(ws + OFF_ET))[cq*NEP + e] = o;
    } else if (bid < NB_A + NB_B) {         // ---- lit -> bf16x4 [29][NEP] ----
        const int idx = bid - NB_A;
        const int ebk = idx % 234;
        const int cq  = (idx / 234) * 4 + (t >> 6);   // 0..31
        const int e   = ebk * 64 + (t & 63);
        if (cq >= 29) return;
        uint2 o = make_uint2(0u, 0u);
        if (e < NE) {
            float4 L = *(const float4*)(lit + e*NL + 4*cq);
            o.x = bf16rne(L.x) | (bf16rne(L.y) << 16);
            o.y = bf16rne(L.z) | (bf16rne(L.w) << 16);
        }
        ((uint2*)(ws + OFF_LT))[cq*NEP + e] = o;
    } else {                                // ---- per-batch prep + WA pack ----
        const int cb  = bid - NB_A - NB_B;  // 0..63
        const int sub = t >> 7;             // 0..1
        const int b   = cb*2 + sub;
        const int tt  = t & 127;
        const int e1 = e1_idx[b];
        const int r  = r_idx[b];
        if (tt < D2) {
            float e1r = E[e1*D + tt],      e1i = E[e1*D + D2 + tt];
            float rr  = R[r*D + tt],       ri  = R[r*D + D2 + tt];
            lwb[sub][tt]      = e1r*rr - e1i*ri;
            lwb[sub][D2 + tt] = e1r*ri + e1i*rr;
        }
        if (tt >= 100 && tt < 124) lwb[sub][100 + tt] = 0.f;   // d = 200..223
        if (tt < NL) {
            float a  = lit[e1*NL + tt] - c[tt];
            float qq = -LOG2E / var[tt];
            // interleaved {u[0..3], f[0..3]} per 4-literal chunk (32B-aligned)
            (ws + OFF_UF)[b*232 + (tt >> 2)*8 + (tt & 3)]     = -2.0f * qq * a;
            (ws + OFF_UF)[b*232 + (tt >> 2)*8 + 4 + (tt & 3)] =
                nf[r*NL + tt] * __builtin_amdgcn_exp2f(qq * a * a);
            if (b == 0) (ws + OFF_NQ)[tt] = qq;
        }
        __syncthreads();
        if (tt < 28) {
            const float* w8 = &lwb[sub][8*tt];
            uint4 o;
            o.x = bf16rne(w8[0]) | (bf16rne(w8[1]) << 16);
            o.y = bf16rne(w8[2]) | (bf16rne(w8[3]) << 16);
            o.z = bf16rne(w8[4]) | (bf16rne(w8[5]) << 16);
            o.w = bf16rne(w8[6]) | (bf16rne(w8[7]) << 16);
            ((uint4*)(ws + OFF_WA))[tt*128 + b] = o;
        }
    }
}

// ---------------- gemm: SL[b][e] = sum_d w[b][d]*E[e][d], bf16 MFMA ----------------
// (unchanged from R13 — verified passing)

__global__ __launch_bounds__(256) void gemm_kernel(
    const uint4* __restrict__ et, const uint4* __restrict__ wa,
    float* __restrict__ sl)
{
    const int gw = blockIdx.x * 4 + (threadIdx.x >> 6);  // 0..7487
    const int l  = threadIdx.x & 63;
    const int mb = gw / 936;            // 0..7   (b-tile)
    const int nb = gw - mb*936;         // 0..935 (e-tile)
    const int lane16 = l & 15;
    const int grp    = l >> 4;
    const int e = nb*16 + lane16;

    f32x4 acc = {0.f, 0.f, 0.f, 0.f};
#pragma unroll
    for (int kc = 0; kc < 7; ++kc) {
        const int s = kc*4 + grp;
        bf16x8 a = *(const bf16x8*)(wa + s*128 + mb*16 + lane16);
        bf16x8 b = *(const bf16x8*)(et + s*NEP + e);
        acc = __builtin_amdgcn_mfma_f32_16x16x32_bf16(a, b, acc, 0, 0, 0);
    }
    const int brow = mb*16 + grp*4;
#pragma unroll
    for (int r = 0; r < 4; ++r)
        sl[(brow + r)*NEP + e] = acc[r];
}

// ---------------- score_n: lane = entity; interleaved uf scalar stream ----------------

#define SN_STEP(lv, cq) do {                                              \
    float L0 = BF2F_LO((lv).x), L1 = BF2F_HI((lv).x);                     \
    float L2 = BF2F_LO((lv).y), L3 = BF2F_HI((lv).y);                     \
    float4 q = *(const float4*)(nq + 4*(cq));                             \
    float g0 = (q.x*L0)*L0, g1 = (q.y*L1)*L1;                             \
    float g2 = (q.z*L2)*L2, g3 = (q.w*L3)*L3;                             \
    _Pragma("unroll")                                                     \
    for (int j = 0; j < EB; ++j) {                                        \
        float4 uj = *(const float4*)(uf + (b0+j)*232 + 8*(cq));           \
        float4 fj = *(const float4*)(uf + (b0+j)*232 + 8*(cq) + 4);       \
        acc[j] = fmaf(fj.x, __builtin_amdgcn_exp2f(fmaf(uj.x, L0, g0)), acc[j]); \
        acc[j] = fmaf(fj.y, __builtin_amdgcn_exp2f(fmaf(uj.y, L1, g1)), acc[j]); \
        acc[j] = fmaf(fj.z, __builtin_amdgcn_exp2f(fmaf(uj.z, L2, g2)), acc[j]); \
        acc[j] = fmaf(fj.w, __builtin_amdgcn_exp2f(fmaf(uj.w, L3, g3)), acc[j]); \
    }                                                                     \
} while (0)

__global__ __launch_bounds__(128) void score_kernel(
    const float* __restrict__ lt4, const float* __restrict__ sl,
    const float* __restrict__ uf,  const float* __restrict__ nq,
    float* __restrict__ out)
{
    // grid = 3744 = 117 eblk * 32 bblk; partition e-range per XCD (lid&7)
    const int lid  = blockIdx.x;
    const int p    = (lid & 7) * 468 + (lid >> 3);
    const int eblk = p >> 5;            // 0..116
    const int bblk = p & 31;            // 0..31
    const int e    = eblk * 128 + threadIdx.x;
    const int b0   = bblk * EB;

    // ---- acc init from MFMA score_l ----
    float acc[EB];
#pragma unroll
    for (int j = 0; j < EB; ++j) acc[j] = sl[(b0+j)*NEP + e];

    const uint2* L4 = (const uint2*)lt4;

    // ---- score_n: 29 bf16x4 chunks, 4-deep rolling prefetch, no clamps ----
    {
        uint2 lv0 = L4[0*NEP + e];
        uint2 lv1 = L4[1*NEP + e];
        uint2 lv2 = L4[2*NEP + e];
        uint2 lv3 = L4[3*NEP + e];
        for (int cq0 = 0; cq0 < 24; cq0 += 4) {
            SN_STEP(lv0, cq0 + 0); lv0 = L4[(cq0 + 4)*NEP + e];
            SN_STEP(lv1, cq0 + 1); lv1 = L4[(cq0 + 5)*NEP + e];
            SN_STEP(lv2, cq0 + 2); lv2 = L4[(cq0 + 6)*NEP + e];
            SN_STEP(lv3, cq0 + 3); lv3 = L4[(cq0 + 7)*NEP + e];
        }
        // slots hold chunks 24..27; one extra load for 28
        SN_STEP(lv0, 24); lv0 = L4[28*NEP + e];
        SN_STEP(lv1, 25);
        SN_STEP(lv2, 26);
        SN_STEP(lv3, 27);
        SN_STEP(lv0, 28);
    }

    // ---- sigmoid + coalesced store ----
    if (e < NE) {
#pragma unroll
        for (int j = 0; j < EB; ++j) {
            float s = __builtin_amdgcn_rcpf(1.0f + __builtin_amdgcn_exp2f(acc[j] * -LOG2E));
            out[(b0+j)*NE + e] = s;
        }
    }
}

// ---------------- legacy fallback (ws too small) ----------------

#define ET  4
#define OFF_W   0
#define OFF_A   25600
#define OFF_WNF 40448
#define OFF_NQL 55296

__global__ __launch_bounds__(128) void prep_kernel_legacy(
    const int* __restrict__ e1_idx, const int* __restrict__ r_idx,
    const float* __restrict__ E, const float* __restrict__ R,
    const float* __restrict__ nf, const float* __restrict__ lit,
    const float* __restrict__ c, const float* __restrict__ var,
    float* __restrict__ ws)
{
    const int b = blockIdx.x;
    const int t = threadIdx.x;
    const int e1 = e1_idx[b];
    const int r  = r_idx[b];
    if (t < D2) {
        float e1r = E[e1*D + t], e1i = E[e1*D + D2 + t];
        float rr  = R[r*D + t],  ri  = R[r*D + D2 + t];
        ws[OFF_W + (t >> 2)*512        + (b << 2) + (t & 3)] = e1r*rr - e1i*ri;
        ws[OFF_W + ((t >> 2) + 25)*512 + (b << 2) + (t & 3)] = e1r*ri + e1i*rr;
    }
    if (t < NL) {
        ws[OFF_A   + (t >> 2)*512 + (b << 2) + (t & 3)] = lit[e1*NL + t] - c[t];
        ws[OFF_WNF + (t >> 2)*512 + (b << 2) + (t & 3)] = nf[r*NL + t];
        if (b == 0) ws[OFF_NQL + t] = -LOG2E / var[t];
    }
}

__global__ __launch_bounds__(128) void main_kernel_legacy(
    const float* __restrict__ E, const float* __restrict__ lit,
    const float* __restrict__ ws, float* __restrict__ out)
{
    const int b  = threadIdx.x;
    const int e0 = blockIdx.x * ET;
    const float4* w4   = (const float4*)(ws + OFF_W);
    const float4* a4   = (const float4*)(ws + OFF_A);
    const float4* wnf4 = (const float4*)(ws + OFF_WNF);
    const float*  nqv  = ws + OFF_NQL;
    int eidx[ET];
#pragma unroll
    for (int j = 0; j < ET; ++j) eidx[j] = min(e0 + j, NE - 1);
    float acc[ET];
#pragma unroll
    for (int j = 0; j < ET; ++j) acc[j] = 0.0f;
    for (int dc = 0; dc < D; dc += 4) {
        float4 wv = w4[(dc >> 2)*B + b];
#pragma unroll
        for (int j = 0; j < ET; ++j) {
            float4 ev = *(const float4*)(E + eidx[j]*D + dc);
            acc[j] = fmaf(wv.x, ev.x, acc[j]);
            acc[j] = fmaf(wv.y, ev.y, acc[j]);
            acc[j] = fmaf(wv.z, ev.z, acc[j]);
            acc[j] = fmaf(wv.w, ev.w, acc[j]);
        }
    }
    for (int lc = 0; lc < NL; lc += 4) {
        float4 av = a4[(lc >> 2)*B + b];
        float4 wv = wnf4[(lc >> 2)*B + b];
        float4 q  = *(const float4*)(nqv + lc);
#pragma unroll
        for (int j = 0; j < ET; ++j) {
            float4 lv = *(const float4*)(lit + eidx[j]*NL + lc);
            float t0 = av.x - lv.x, t1 = av.y - lv.y, t2 = av.z - lv.z, t3 = av.w - lv.w;
            acc[j] += wv.x * __builtin_amdgcn_exp2f(t0*t0*q.x);
            acc[j] += wv.y * __builtin_amdgcn_exp2f(t1*t1*q.y);
            acc[j] += wv.z * __builtin_amdgcn_exp2f(t2*t2*q.z);
            acc[j] += wv.w * __builtin_amdgcn_exp2f(t3*t3*q.w);
        }
    }
#pragma unroll
    for (int j = 0; j < ET; ++j) {
        float s = 1.0f / (1.0f + __builtin_amdgcn_exp2f(acc[j] * -LOG2E));
        int e = e0 + j;
        if (e < NE) out[b*NE + e] = s;
    }
}

// ---------------- launch ----------------

extern "C" void kernel_launch(void* const* d_in, const int* in_sizes, int n_in,
                              void* d_out, int out_size, void* d_ws, size_t ws_size,
                              hipStream_t stream) {
    const int*   e1_idx = (const int*)d_in[0];
    const int*   r_idx  = (const int*)d_in[1];
    const float* E      = (const float*)d_in[2];
    const float* R      = (const float*)d_in[3];
    const float* nf     = (const float*)d_in[4];
    const float* lit    = (const float*)d_in[5];
    const float* c      = (const float*)d_in[6];
    const float* var    = (const float*)d_in[7];
    float* out = (float*)d_out;
    float* ws  = (float*)d_ws;

    if (ws_size >= WS_NEEDED) {
        prep_all<<<NB_A + NB_B + NB_C, 256, 0, stream>>>(
            e1_idx, r_idx, E, R, nf, lit, c, var, ws);
        gemm_kernel<<<1872, 256, 0, stream>>>(
            (const uint4*)(ws + OFF_ET), (const uint4*)(ws + OFF_WA), ws + OFF_SL);
        score_kernel<<<3744, 128, 0, stream>>>(
            ws + OFF_LT, ws + OFF_SL, ws + OFF_UF, ws + OFF_NQ, out);
    } else {
        prep_kernel_legacy<<<B, 128, 0, stream>>>(e1_idx, r_idx, E, R, nf, lit, c, var, ws);
        main_kernel_legacy<<<(NE + ET - 1)/ET, B, 0, stream>>>(E, lit, ws, out);
    }
}

// Round 18
// 53.555 us; speedup vs baseline: 1.0794x; 1.0566x over previous
//
#include <hip/hip_runtime.h>

#define B     128
#define NE    14951
#define NEP   14976     // 117*128 = 936*16, padded entity count
#define NR    1345
#define D     200
#define NL    116
#define D2    100
#define EB    4
#define LOG2E 1.4426950408889634f

typedef __attribute__((ext_vector_type(8))) short bf16x8;
typedef __attribute__((ext_vector_type(4))) float f32x4;

// ---- ws layout (floats), fast path ----
#define OFF_ET   0                            // uint4[28][NEP] : E bf16x8, slot s = d 8s..8s+7 (d>=200 zero)
#define OFF_WA   (OFF_ET + 28*NEP*4)          // uint4[28][128] : w  bf16x8, same k-chunking
#define OFF_LT   (OFF_WA + 28*128*4)          // uint2[29][NEP] : lit bf16x4
#define OFF_SL   (OFF_LT + 29*NEP*2)          // float[128][NEP]: score_l
#define OFF_UB   (OFF_SL + 128*NEP)           // [128][116] fp32: u = -2*q*a
#define OFF_FB   (OFF_UB + 128*116)           // [128][116] fp32: w' = wnf*exp2(q*a^2)
#define OFF_NQ   (OFF_FB + 128*116)           // [116] fp32     : q
#define WS_FLOATS (OFF_NQ + 128)
#define WS_NEEDED ((size_t)WS_FLOATS * 4)

__device__ __forceinline__ unsigned bf16rne(float f) {
    unsigned u = __float_as_uint(f);
    u += 0x7FFFu + ((u >> 16) & 1u);
    return u >> 16;
}
#define BF2F_LO(u) __uint_as_float((u) << 16)
#define BF2F_HI(u) __uint_as_float((u) & 0xffff0000u)

// ---------------- fused prep: 3 roles by blockIdx range ----------------
// role A: E -> ET bf16x8 [28][NEP]  : 234 * 7 = 1638 blocks
// role B: lit -> LT bf16x4 [29][NEP]: 234 * 8 = 1872 blocks
// role C: per-batch prep + WA pack  : 64 blocks (2 b each)
#define NB_A 1638
#define NB_B 1872
#define NB_C 64

__global__ __launch_bounds__(256) void prep_all(
    const int* __restrict__ e1_idx, const int* __restrict__ r_idx,
    const float* __restrict__ E, const float* __restrict__ R,
    const float* __restrict__ nf, const float* __restrict__ lit,
    const float* __restrict__ c, const float* __restrict__ var,
    float* __restrict__ ws)
{
    __shared__ float lwb[2][224];
    const int bid = blockIdx.x;
    const int t   = threadIdx.x;

    if (bid < NB_A) {                       // ---- E -> bf16x8 [28][NEP] ----
        const int ebk = bid % 234;
        const int cq  = (bid / 234) * 4 + (t >> 6);   // 0..27
        const int e   = ebk * 64 + (t & 63);
        uint4 o = make_uint4(0u, 0u, 0u, 0u);
        if (e < NE && cq < 25) {            // d = 8cq..8cq+7 < 200
            float4 a = *(const float4*)(E + e*D + 8*cq);
            float4 b = *(const float4*)(E + e*D + 8*cq + 4);
            o.x = bf16rne(a.x) | (bf16rne(a.y) << 16);
            o.y = bf16rne(a.z) | (bf16rne(a.w) << 16);
            o.z = bf16rne(b.x) | (bf16rne(b.y) << 16);
            o.w = bf16rne(b.z) | (bf16rne(b.w) << 16);
        }
        ((uint4*)(ws + OFF_ET))[cq*NEP + e] = o;
    } else if (bid < NB_A + NB_B) {         // ---- lit -> bf16x4 [29][NEP] ----
        const int idx = bid - NB_A;
        const int ebk = idx % 234;
        const int cq  = (idx / 234) * 4 + (t >> 6);   // 0..31
        const int e   = ebk * 64 + (t & 63);
        if (cq >= 29) return;
        uint2 o = make_uint2(0u, 0u);
        if (e < NE) {
            float4 L = *(const float4*)(lit + e*NL + 4*cq);
            o.x = bf16rne(L.x) | (bf16rne(L.y) << 16);
            o.y = bf16rne(L.z) | (bf16rne(L.w) << 16);
        }
        ((uint2*)(ws + OFF_LT))[cq*NEP + e] = o;
    } else {                                // ---- per-batch prep + WA pack ----
        const int cb  = bid - NB_A - NB_B;  // 0..63
        const int sub = t >> 7;             // 0..1
        const int b   = cb*2 + sub;
        const int tt  = t & 127;
        const int e1 = e1_idx[b];
        const int r  = r_idx[b];
        if (tt < D2) {
            float e1r = E[e1*D + tt],      e1i = E[e1*D + D2 + tt];
            float rr  = R[r*D + tt],       ri  = R[r*D + D2 + tt];
            lwb[sub][tt]      = e1r*rr - e1i*ri;
            lwb[sub][D2 + tt] = e1r*ri + e1i*rr;
        }
        if (tt >= 100 && tt < 124) lwb[sub][100 + tt] = 0.f;   // d = 200..223
        if (tt < NL) {
            float a = lit[e1*NL + tt] - c[tt];
            float qq = -LOG2E / var[tt];
            (ws + OFF_UB)[b*NL + tt] = -2.0f * qq * a;
            (ws + OFF_FB)[b*NL + tt] = nf[r*NL + tt] * __builtin_amdgcn_exp2f(qq * a * a);
            if (b == 0) (ws + OFF_NQ)[tt] = qq;
        }
        __syncthreads();
        if (tt < 28) {
            const float* w8 = &lwb[sub][8*tt];
            uint4 o;
            o.x = bf16rne(w8[0]) | (bf16rne(w8[1]) << 16);
            o.y = bf16rne(w8[2]) | (bf16rne(w8[3]) << 16);
            o.z = bf16rne(w8[4]) | (bf16rne(w8[5]) << 16);
            o.w = bf16rne(w8[6]) | (bf16rne(w8[7]) << 16);
            ((uint4*)(ws + OFF_WA))[tt*128 + b] = o;
        }
    }
}

// ---------------- gemm: SL[b][e] = sum_d w[b][d]*E[e][d], bf16 MFMA ----------------

__global__ __launch_bounds__(256) void gemm_kernel(
    const uint4* __restrict__ et, const uint4* __restrict__ wa,
    float* __restrict__ sl)
{
    const int gw = blockIdx.x * 4 + (threadIdx.x >> 6);  // 0..7487
    const int l  = threadIdx.x & 63;
    const int mb = gw / 936;            // 0..7   (b-tile)
    const int nb = gw - mb*936;         // 0..935 (e-tile)
    const int lane16 = l & 15;
    const int grp    = l >> 4;
    const int e = nb*16 + lane16;

    f32x4 acc = {0.f, 0.f, 0.f, 0.f};
#pragma unroll
    for (int kc = 0; kc < 7; ++kc) {
        const int s = kc*4 + grp;
        bf16x8 a = *(const bf16x8*)(wa + s*128 + mb*16 + lane16);
        bf16x8 b = *(const bf16x8*)(et + s*NEP + e);
        acc = __builtin_amdgcn_mfma_f32_16x16x32_bf16(a, b, acc, 0, 0, 0);
    }
    const int brow = mb*16 + grp*4;
#pragma unroll
    for (int r = 0; r < 4; ++r)
        sl[(brow + r)*NEP + e] = acc[r];
}

// ---------------- score_n: lane = entity; scalar batch operands ----------------

#define SN_STEP(lv, cq) do {                                              \
    float L0 = BF2F_LO((lv).x), L1 = BF2F_HI((lv).x);                     \
    float L2 = BF2F_LO((lv).y), L3 = BF2F_HI((lv).y);                     \
    float4 q = *(const float4*)(nq + 4*(cq));                             \
    float g0 = (q.x*L0)*L0, g1 = (q.y*L1)*L1;                             \
    float g2 = (q.z*L2)*L2, g3 = (q.w*L3)*L3;                             \
    _Pragma("unroll")                                                     \
    for (int j = 0; j < EB; ++j) {                                        \
        float4 uj = *(const float4*)(ub + (b0+j)*NL + 4*(cq));            \
        float4 fj = *(const float4*)(fb + (b0+j)*NL + 4*(cq));            \
        acc[j] = fmaf(fj.x, __builtin_amdgcn_exp2f(fmaf(uj.x, L0, g0)), acc[j]); \
        acc[j] = fmaf(fj.y, __builtin_amdgcn_exp2f(fmaf(uj.y, L1, g1)), acc[j]); \
        acc[j] = fmaf(fj.z, __builtin_amdgcn_exp2f(fmaf(uj.z, L2, g2)), acc[j]); \
        acc[j] = fmaf(fj.w, __builtin_amdgcn_exp2f(fmaf(uj.w, L3, g3)), acc[j]); \
    }                                                                     \
} while (0)

__global__ __launch_bounds__(128) void score_kernel(
    const float* __restrict__ lt4, const float* __restrict__ sl,
    const float* __restrict__ ub,  const float* __restrict__ fb,
    const float* __restrict__ nq,  float* __restrict__ out)
{
    // grid = 3744 = 117 eblk * 32 bblk; partition e-range per XCD (lid&7)
    const int lid  = blockIdx.x;
    const int p    = (lid & 7) * 468 + (lid >> 3);
    const int eblk = p >> 5;            // 0..116
    const int bblk = p & 31;            // 0..31
    const int e    = eblk * 128 + threadIdx.x;
    const int b0   = bblk * EB;

    // ---- acc init from MFMA score_l ----
    float acc[EB];
#pragma unroll
    for (int j = 0; j < EB; ++j) acc[j] = sl[(b0+j)*NEP + e];

    const uint2* L4 = (const uint2*)lt4;

    // ---- score_n: 29 bf16x4 chunks, 4-deep rolling prefetch, no clamps ----
    {
        uint2 lv0 = L4[0*NEP + e];
        uint2 lv1 = L4[1*NEP + e];
        uint2 lv2 = L4[2*NEP + e];
        uint2 lv3 = L4[3*NEP + e];
        for (int cq0 = 0; cq0 < 24; cq0 += 4) {
            SN_STEP(lv0, cq0 + 0); lv0 = L4[(cq0 + 4)*NEP + e];
            SN_STEP(lv1, cq0 + 1); lv1 = L4[(cq0 + 5)*NEP + e];
            SN_STEP(lv2, cq0 + 2); lv2 = L4[(cq0 + 6)*NEP + e];
            SN_STEP(lv3, cq0 + 3); lv3 = L4[(cq0 + 7)*NEP + e];
        }
        // slots hold chunks 24..27; one extra load for 28
        SN_STEP(lv0, 24); lv0 = L4[28*NEP + e];
        SN_STEP(lv1, 25);
        SN_STEP(lv2, 26);
        SN_STEP(lv3, 27);
        SN_STEP(lv0, 28);
    }

    // ---- sigmoid + coalesced store ----
    if (e < NE) {
#pragma unroll
        for (int j = 0; j < EB; ++j) {
            float s = __builtin_amdgcn_rcpf(1.0f + __builtin_amdgcn_exp2f(acc[j] * -LOG2E));
            out[(b0+j)*NE + e] = s;
        }
    }
}

// ---------------- legacy fallback (ws too small) ----------------

#define ET  4
#define OFF_W   0
#define OFF_A   25600
#define OFF_WNF 40448
#define OFF_NQL 55296

__global__ __launch_bounds__(128) void prep_kernel_legacy(
    const int* __restrict__ e1_idx, const int* __restrict__ r_idx,
    const float* __restrict__ E, const float* __restrict__ R,
    const float* __restrict__ nf, const float* __restrict__ lit,
    const float* __restrict__ c, const float* __restrict__ var,
    float* __restrict__ ws)
{
    const int b = blockIdx.x;
    const int t = threadIdx.x;
    const int e1 = e1_idx[b];
    const int r  = r_idx[b];
    if (t < D2) {
        float e1r = E[e1*D + t], e1i = E[e1*D + D2 + t];
        float rr  = R[r*D + t],  ri  = R[r*D + D2 + t];
        ws[OFF_W + (t >> 2)*512        + (b << 2) + (t & 3)] = e1r*rr - e1i*ri;
        ws[OFF_W + ((t >> 2) + 25)*512 + (b << 2) + (t & 3)] = e1r*ri + e1i*rr;
    }
    if (t < NL) {
        ws[OFF_A   + (t >> 2)*512 + (b << 2) + (t & 3)] = lit[e1*NL + t] - c[t];
        ws[OFF_WNF + (t >> 2)*512 + (b << 2) + (t & 3)] = nf[r*NL + t];
        if (b == 0) ws[OFF_NQL + t] = -LOG2E / var[t];
    }
}

__global__ __launch_bounds__(128) void main_kernel_legacy(
    const float* __restrict__ E, const float* __restrict__ lit,
    const float* __restrict__ ws, float* __restrict__ out)
{
    const int b  = threadIdx.x;
    const int e0 = blockIdx.x * ET;
    const float4* w4   = (const float4*)(ws + OFF_W);
    const float4* a4   = (const float4*)(ws + OFF_A);
    const float4* wnf4 = (const float4*)(ws + OFF_WNF);
    const float*  nqv  = ws + OFF_NQL;
    int eidx[ET];
#pragma unroll
    for (int j = 0; j < ET; ++j) eidx[j] = min(e0 + j, NE - 1);
    float acc[ET];
#pragma unroll
    for (int j = 0; j < ET; ++j) acc[j] = 0.0f;
    for (int dc = 0; dc < D; dc += 4) {
        float4 wv = w4[(dc >> 2)*B + b];
#pragma unroll
        for (int j = 0; j < ET; ++j) {
            float4 ev = *(const float4*)(E + eidx[j]*D + dc);
            acc[j] = fmaf(wv.x, ev.x, acc[j]);
            acc[j] = fmaf(wv.y, ev.y, acc[j]);
            acc[j] = fmaf(wv.z, ev.z, acc[j]);
            acc[j] = fmaf(wv.w, ev.w, acc[j]);
        }
    }
    for (int lc = 0; lc < NL; lc += 4) {
        float4 av = a4[(lc >> 2)*B + b];
        float4 wv = wnf4[(lc >> 2)*B + b];
        float4 q  = *(const float4*)(nqv + lc);
#pragma unroll
        for (int j = 0; j < ET; ++j) {
            float4 lv = *(const float4*)(lit + eidx[j]*NL + lc);
            float t0 = av.x - lv.x, t1 = av.y - lv.y, t2 = av.z - lv.z, t3 = av.w - lv.w;
            acc[j] += wv.x * __builtin_amdgcn_exp2f(t0*t0*q.x);
            acc[j] += wv.y * __builtin_amdgcn_exp2f(t1*t1*q.y);
            acc[j] += wv.z * __builtin_amdgcn_exp2f(t2*t2*q.z);
            acc[j] += wv.w * __builtin_amdgcn_exp2f(t3*t3*q.w);
        }
    }
#pragma unroll
    for (int j = 0; j < ET; ++j) {
        float s = 1.0f / (1.0f + __builtin_amdgcn_exp2f(acc[j] * -LOG2E));
        int e = e0 + j;
        if (e < NE) out[b*NE + e] = s;
    }
}

// ---------------- launch ----------------

extern "C" void kernel_launch(void* const* d_in, const int* in_sizes, int n_in,
                              void* d_out, int out_size, void* d_ws, size_t ws_size,
                              hipStream_t stream) {
    const int*   e1_idx = (const int*)d_in[0];
    const int*   r_idx  = (const int*)d_in[1];
    const float* E      = (const float*)d_in[2];
    const float* R      = (const float*)d_in[3];
    const float* nf     = (const float*)d_in[4];
    const float* lit    = (const float*)d_in[5];
    const float* c      = (const float*)d_in[6];
    const float* var    = (const float*)d_in[7];
    float* out = (float*)d_out;
    float* ws  = (float*)d_ws;

    if (ws_size >= WS_NEEDED) {
        prep_all<<<NB_A + NB_B + NB_C, 256, 0, stream>>>(
            e1_idx, r_idx, E, R, nf, lit, c, var, ws);
        gemm_kernel<<<1872, 256, 0, stream>>>(
            (const uint4*)(ws + OFF_ET), (const uint4*)(ws + OFF_WA), ws + OFF_SL);
        score_kernel<<<3744, 128, 0, stream>>>(
            ws + OFF_LT, ws + OFF_SL, ws + OFF_UB, ws + OFF_FB, ws + OFF_NQ, out);
    } else {
        prep_kernel_legacy<<<B, 128, 0, stream>>>(e1_idx, r_idx, E, R, nf, lit, c, var, ws);
        main_kernel_legacy<<<(NE + ET - 1)/ET, B, 0, stream>>>(E, lit, ws, out);
    }
}

// Round 19
// 51.803 us; speedup vs baseline: 1.1159x; 1.0338x over previous
//
#include <hip/hip_runtime.h>

#define B     128
#define NE    14951
#define NEP   14976     // 117*128 = 936*16, padded entity count
#define NR    1345
#define D     200
#define NL    116
#define D2    100
#define EB    4
#define LOG2E 1.4426950408889634f

typedef __attribute__((ext_vector_type(8))) short bf16x8;
typedef __attribute__((ext_vector_type(4))) float f32x4;

// ---- ws layout (floats), fast path ----
#define OFF_ET   0                            // uint4[28][NEP] : E bf16x8, slot s = d 8s..8s+7 (d>=200 zero)
#define OFF_WA   (OFF_ET + 28*NEP*4)          // uint4[28][128] : w  bf16x8, same k-chunking
#define OFF_LT   (OFF_WA + 28*128*4)          // uint2[29][NEP] : lit bf16x4
#define OFF_SL   (OFF_LT + 29*NEP*2)          // float[128][NEP]: score_l
#define OFF_UB   (OFF_SL + 128*NEP)           // [128][116] fp32: u = -2*q*a
#define OFF_FB   (OFF_UB + 128*116)           // [128][116] fp32: w' = wnf*exp2(q*a^2)
#define OFF_NQ   (OFF_FB + 128*116)           // [116] fp32     : q
#define WS_FLOATS (OFF_NQ + 128)
#define WS_NEEDED ((size_t)WS_FLOATS * 4)

__device__ __forceinline__ unsigned bf16rne(float f) {
    unsigned u = __float_as_uint(f);
    u += 0x7FFFu + ((u >> 16) & 1u);
    return u >> 16;
}
#define BF2F_LO(u) __uint_as_float((u) << 16)
#define BF2F_HI(u) __uint_as_float((u) & 0xffff0000u)

// ---------------- fused prep: 3 roles by blockIdx range ----------------
// role A: E -> ET bf16x8 [28][NEP]  : 234 * 7 = 1638 blocks
// role B: lit -> LT bf16x4 [29][NEP]: 234 * 8 = 1872 blocks
// role C: per-batch prep + WA pack  : 64 blocks (2 b each)
#define NB_A 1638
#define NB_B 1872
#define NB_C 64

__global__ __launch_bounds__(256) void prep_all(
    const int* __restrict__ e1_idx, const int* __restrict__ r_idx,
    const float* __restrict__ E, const float* __restrict__ R,
    const float* __restrict__ nf, const float* __restrict__ lit,
    const float* __restrict__ c, const float* __restrict__ var,
    float* __restrict__ ws)
{
    __shared__ float lwb[2][224];
    const int bid = blockIdx.x;
    const int t   = threadIdx.x;

    if (bid < NB_A) {                       // ---- E -> bf16x8 [28][NEP] ----
        const int ebk = bid % 234;
        const int cq  = (bid / 234) * 4 + (t >> 6);   // 0..27
        const int e   = ebk * 64 + (t & 63);
        uint4 o = make_uint4(0u, 0u, 0u, 0u);
        if (e < NE && cq < 25) {            // d = 8cq..8cq+7 < 200
            float4 a = *(const float4*)(E + e*D + 8*cq);
            float4 b = *(const float4*)(E + e*D + 8*cq + 4);
            o.x = bf16rne(a.x) | (bf16rne(a.y) << 16);
            o.y = bf16rne(a.z) | (bf16rne(a.w) << 16);
            o.z = bf16rne(b.x) | (bf16rne(b.y) << 16);
            o.w = bf16rne(b.z) | (bf16rne(b.w) << 16);
        }
        ((uint4*)(ws + OFF_ET))[cq*NEP + e] = o;
    } else if (bid < NB_A + NB_B) {         // ---- lit -> bf16x4 [29][NEP] ----
        const int idx = bid - NB_A;
        const int ebk = idx % 234;
        const int cq  = (idx / 234) * 4 + (t >> 6);   // 0..31
        const int e   = ebk * 64 + (t & 63);
        if (cq >= 29) return;
        uint2 o = make_uint2(0u, 0u);
        if (e < NE) {
            float4 L = *(const float4*)(lit + e*NL + 4*cq);
            o.x = bf16rne(L.x) | (bf16rne(L.y) << 16);
            o.y = bf16rne(L.z) | (bf16rne(L.w) << 16);
        }
        ((uint2*)(ws + OFF_LT))[cq*NEP + e] = o;
    } else {                                // ---- per-batch prep + WA pack ----
        const int cb  = bid - NB_A - NB_B;  // 0..63
        const int sub = t >> 7;             // 0..1
        const int b   = cb*2 + sub;
        const int tt  = t & 127;
        const int e1 = e1_idx[b];
        const int r  = r_idx[b];
        if (tt < D2) {
            float e1r = E[e1*D + tt],      e1i = E[e1*D + D2 + tt];
            float rr  = R[r*D + tt],       ri  = R[r*D + D2 + tt];
            lwb[sub][tt]      = e1r*rr - e1i*ri;
            lwb[sub][D2 + tt] = e1r*ri + e1i*rr;
        }
        if (tt >= 100 && tt < 124) lwb[sub][100 + tt] = 0.f;   // d = 200..223
        if (tt < NL) {
            float a = lit[e1*NL + tt] - c[tt];
            float qq = -LOG2E / var[tt];
            (ws + OFF_UB)[b*NL + tt] = -2.0f * qq * a;
            (ws + OFF_FB)[b*NL + tt] = nf[r*NL + tt] * __builtin_amdgcn_exp2f(qq * a * a);
            if (b == 0) (ws + OFF_NQ)[tt] = qq;
        }
        __syncthreads();
        if (tt < 28) {
            const float* w8 = &lwb[sub][8*tt];
            uint4 o;
            o.x = bf16rne(w8[0]) | (bf16rne(w8[1]) << 16);
            o.y = bf16rne(w8[2]) | (bf16rne(w8[3]) << 16);
            o.z = bf16rne(w8[4]) | (bf16rne(w8[5]) << 16);
            o.w = bf16rne(w8[6]) | (bf16rne(w8[7]) << 16);
            ((uint4*)(ws + OFF_WA))[tt*128 + b] = o;
        }
    }
}

// ---------------- gemm: SL[b][e] = sum_d w[b][d]*E[e][d], bf16 MFMA ----------------
// One wave per nb e-tile; loops ALL 8 mb b-tiles over a single ET read
// (ET L2 traffic 54 -> 6.7 MB). Accumulation order per acc identical to R13.

__global__ __launch_bounds__(256) void gemm_kernel(
    const uint4* __restrict__ et, const uint4* __restrict__ wa,
    float* __restrict__ sl)
{
    const int nb = blockIdx.x * 4 + (threadIdx.x >> 6);  // 0..935 (e-tile)
    const int l  = threadIdx.x & 63;
    const int lane16 = l & 15;
    const int grp    = l >> 4;
    const int e = nb*16 + lane16;

    f32x4 acc[8];
#pragma unroll
    for (int mb = 0; mb < 8; ++mb) acc[mb] = {0.f, 0.f, 0.f, 0.f};

#pragma unroll
    for (int kc = 0; kc < 7; ++kc) {
        const int s = kc*4 + grp;
        bf16x8 bfrag = *(const bf16x8*)(et + s*NEP + e);
#pragma unroll
        for (int mb = 0; mb < 8; ++mb) {
            bf16x8 a = *(const bf16x8*)(wa + s*128 + mb*16 + lane16);
            acc[mb] = __builtin_amdgcn_mfma_f32_16x16x32_bf16(a, bfrag, acc[mb], 0, 0, 0);
        }
    }
#pragma unroll
    for (int mb = 0; mb < 8; ++mb) {
        const int brow = mb*16 + grp*4;
#pragma unroll
        for (int r = 0; r < 4; ++r)
            sl[(brow + r)*NEP + e] = acc[mb][r];
    }
}

// ---------------- score_n: lane = entity; scalar batch operands ----------------

#define SN_STEP(lv, cq) do {                                              \
    float L0 = BF2F_LO((lv).x), L1 = BF2F_HI((lv).x);                     \
    float L2 = BF2F_LO((lv).y), L3 = BF2F_HI((lv).y);                     \
    float4 q = *(const float4*)(nq + 4*(cq));                             \
    float g0 = (q.x*L0)*L0, g1 = (q.y*L1)*L1;                             \
    float g2 = (q.z*L2)*L2, g3 = (q.w*L3)*L3;                             \
    _Pragma("unroll")                                                     \
    for (int j = 0; j < EB; ++j) {                                        \
        float4 uj = *(const float4*)(ub + (b0+j)*NL + 4*(cq));            \
        float4 fj = *(const float4*)(fb + (b0+j)*NL + 4*(cq));            \
        acc[j] = fmaf(fj.x, __builtin_amdgcn_exp2f(fmaf(uj.x, L0, g0)), acc[j]); \
        acc[j] = fmaf(fj.y, __builtin_amdgcn_exp2f(fmaf(uj.y, L1, g1)), acc[j]); \
        acc[j] = fmaf(fj.z, __builtin_amdgcn_exp2f(fmaf(uj.z, L2, g2)), acc[j]); \
        acc[j] = fmaf(fj.w, __builtin_amdgcn_exp2f(fmaf(uj.w, L3, g3)), acc[j]); \
    }                                                                     \
} while (0)

__global__ __launch_bounds__(128) void score_kernel(
    const float* __restrict__ lt4, const float* __restrict__ sl,
    const float* __restrict__ ub,  const float* __restrict__ fb,
    const float* __restrict__ nq,  float* __restrict__ out)
{
    // grid = 3744 = 117 eblk * 32 bblk; partition e-range per XCD (lid&7)
    const int lid  = blockIdx.x;
    const int p    = (lid & 7) * 468 + (lid >> 3);
    const int eblk = p >> 5;            // 0..116
    const int bblk = p & 31;            // 0..31
    const int e    = eblk * 128 + threadIdx.x;
    const int b0   = bblk * EB;

    // ---- acc init from MFMA score_l ----
    float acc[EB];
#pragma unroll
    for (int j = 0; j < EB; ++j) acc[j] = sl[(b0+j)*NEP + e];

    const uint2* L4 = (const uint2*)lt4;

    // ---- score_n: 29 bf16x4 chunks, 4-deep rolling prefetch, no clamps ----
    {
        uint2 lv0 = L4[0*NEP + e];
        uint2 lv1 = L4[1*NEP + e];
        uint2 lv2 = L4[2*NEP + e];
        uint2 lv3 = L4[3*NEP + e];
        for (int cq0 = 0; cq0 < 24; cq0 += 4) {
            SN_STEP(lv0, cq0 + 0); lv0 = L4[(cq0 + 4)*NEP + e];
            SN_STEP(lv1, cq0 + 1); lv1 = L4[(cq0 + 5)*NEP + e];
            SN_STEP(lv2, cq0 + 2); lv2 = L4[(cq0 + 6)*NEP + e];
            SN_STEP(lv3, cq0 + 3); lv3 = L4[(cq0 + 7)*NEP + e];
        }
        // slots hold chunks 24..27; one extra load for 28
        SN_STEP(lv0, 24); lv0 = L4[28*NEP + e];
        SN_STEP(lv1, 25);
        SN_STEP(lv2, 26);
        SN_STEP(lv3, 27);
        SN_STEP(lv0, 28);
    }

    // ---- sigmoid + coalesced store ----
    if (e < NE) {
#pragma unroll
        for (int j = 0; j < EB; ++j) {
            float s = __builtin_amdgcn_rcpf(1.0f + __builtin_amdgcn_exp2f(acc[j] * -LOG2E));
            out[(b0+j)*NE + e] = s;
        }
    }
}

// ---------------- legacy fallback (ws too small) ----------------

#define ET  4
#define OFF_W   0
#define OFF_A   25600
#define OFF_WNF 40448
#define OFF_NQL 55296

__global__ __launch_bounds__(128) void prep_kernel_legacy(
    const int* __restrict__ e1_idx, const int* __restrict__ r_idx,
    const float* __restrict__ E, const float* __restrict__ R,
    const float* __restrict__ nf, const float* __restrict__ lit,
    const float* __restrict__ c, const float* __restrict__ var,
    float* __restrict__ ws)
{
    const int b = blockIdx.x;
    const int t = threadIdx.x;
    const int e1 = e1_idx[b];
    const int r  = r_idx[b];
    if (t < D2) {
        float e1r = E[e1*D + t], e1i = E[e1*D + D2 + t];
        float rr  = R[r*D + t],  ri  = R[r*D + D2 + t];
        ws[OFF_W + (t >> 2)*512        + (b << 2) + (t & 3)] = e1r*rr - e1i*ri;
        ws[OFF_W + ((t >> 2) + 25)*512 + (b << 2) + (t & 3)] = e1r*ri + e1i*rr;
    }
    if (t < NL) {
        ws[OFF_A   + (t >> 2)*512 + (b << 2) + (t & 3)] = lit[e1*NL + t] - c[t];
        ws[OFF_WNF + (t >> 2)*512 + (b << 2) + (t & 3)] = nf[r*NL + t];
        if (b == 0) ws[OFF_NQL + t] = -LOG2E / var[t];
    }
}

__global__ __launch_bounds__(128) void main_kernel_legacy(
    const float* __restrict__ E, const float* __restrict__ lit,
    const float* __restrict__ ws, float* __restrict__ out)
{
    const int b  = threadIdx.x;
    const int e0 = blockIdx.x * ET;
    const float4* w4   = (const float4*)(ws + OFF_W);
    const float4* a4   = (const float4*)(ws + OFF_A);
    const float4* wnf4 = (const float4*)(ws + OFF_WNF);
    const float*  nqv  = ws + OFF_NQL;
    int eidx[ET];
#pragma unroll
    for (int j = 0; j < ET; ++j) eidx[j] = min(e0 + j, NE - 1);
    float acc[ET];
#pragma unroll
    for (int j = 0; j < ET; ++j) acc[j] = 0.0f;
    for (int dc = 0; dc < D; dc += 4) {
        float4 wv = w4[(dc >> 2)*B + b];
#pragma unroll
        for (int j = 0; j < ET; ++j) {
            float4 ev = *(const float4*)(E + eidx[j]*D + dc);
            acc[j] = fmaf(wv.x, ev.x, acc[j]);
            acc[j] = fmaf(wv.y, ev.y, acc[j]);
            acc[j] = fmaf(wv.z, ev.z, acc[j]);
            acc[j] = fmaf(wv.w, ev.w, acc[j]);
        }
    }
    for (int lc = 0; lc < NL; lc += 4) {
        float4 av = a4[(lc >> 2)*B + b];
        float4 wv = wnf4[(lc >> 2)*B + b];
        float4 q  = *(const float4*)(nqv + lc);
#pragma unroll
        for (int j = 0; j < ET; ++j) {
            float4 lv = *(const float4*)(lit + eidx[j]*NL + lc);
            float t0 = av.x - lv.x, t1 = av.y - lv.y, t2 = av.z - lv.z, t3 = av.w - lv.w;
            acc[j] += wv.x * __builtin_amdgcn_exp2f(t0*t0*q.x);
            acc[j] += wv.y * __builtin_amdgcn_exp2f(t1*t1*q.y);
            acc[j] += wv.z * __builtin_amdgcn_exp2f(t2*t2*q.z);
            acc[j] += wv.w * __builtin_amdgcn_exp2f(t3*t3*q.w);
        }
    }
#pragma unroll
    for (int j = 0; j < ET; ++j) {
        float s = 1.0f / (1.0f + __builtin_amdgcn_exp2f(acc[j] * -LOG2E));
        int e = e0 + j;
        if (e < NE) out[b*NE + e] = s;
    }
}

// ---------------- launch ----------------

extern "C" void kernel_launch(void* const* d_in, const int* in_sizes, int n_in,
                              void* d_out, int out_size, void* d_ws, size_t ws_size,
                              hipStream_t stream) {
    const int*   e1_idx = (const int*)d_in[0];
    const int*   r_idx  = (const int*)d_in[1];
    const float* E      = (const float*)d_in[2];
    const float* R      = (const float*)d_in[3];
    const float* nf     = (const float*)d_in[4];
    const float* lit    = (const float*)d_in[5];
    const float* c      = (const float*)d_in[6];
    const float* var    = (const float*)d_in[7];
    float* out = (float*)d_out;
    float* ws  = (float*)d_ws;

    if (ws_size >= WS_NEEDED) {
        prep_all<<<NB_A + NB_B + NB_C, 256, 0, stream>>>(
            e1_idx, r_idx, E, R, nf, lit, c, var, ws);
        gemm_kernel<<<234, 256, 0, stream>>>(
            (const uint4*)(ws + OFF_ET), (const uint4*)(ws + OFF_WA), ws + OFF_SL);
        score_kernel<<<3744, 128, 0, stream>>>(
            ws + OFF_LT, ws + OFF_SL, ws + OFF_UB, ws + OFF_FB, ws + OFF_NQ, out);
    } else {
        prep_kernel_legacy<<<B, 128, 0, stream>>>(e1_idx, r_idx, E, R, nf, lit, c, var, ws);
        main_kernel_legacy<<<(NE + ET - 1)/ET, B, 0, stream>>>(E, lit, ws, out);
    }
}

// Round 20
// 51.303 us; speedup vs baseline: 1.1268x; 1.0098x over previous
//
#include <hip/hip_runtime.h>

#define B     128
#define NE    14951
#define NEP   14976     // 117*128 = 936*16, padded entity count
#define NR    1345
#define D     200
#define NL    116
#define D2    100
#define EB    4
#define LOG2E 1.4426950408889634f

typedef __attribute__((ext_vector_type(8))) short bf16x8;
typedef __attribute__((ext_vector_type(4))) float f32x4;

// ---- ws layout (floats), fast path ----
#define OFF_WA   0                            // uint4[28][128] : w bf16x8, k-chunked (slot s = d 8s..8s+7)
#define OFF_LT   (OFF_WA + 28*128*4)          // uint2[29][NEP] : lit bf16x4
#define OFF_SL   (OFF_LT + 29*NEP*2)          // float[128][NEP]: score_l
#define OFF_UB   (OFF_SL + 128*NEP)           // [128][116] fp32: u = -2*q*a
#define OFF_FB   (OFF_UB + 128*116)           // [128][116] fp32: w' = wnf*exp2(q*a^2)
#define OFF_NQ   (OFF_FB + 128*116)           // [116] fp32     : q
#define WS_FLOATS (OFF_NQ + 128)
#define WS_NEEDED ((size_t)WS_FLOATS * 4)

__device__ __forceinline__ unsigned bf16rne(float f) {
    unsigned u = __float_as_uint(f);
    u += 0x7FFFu + ((u >> 16) & 1u);
    return u >> 16;
}
#define BF2F_LO(u) __uint_as_float((u) << 16)
#define BF2F_HI(u) __uint_as_float((u) & 0xffff0000u)

// ---------------- fused prep: 2 roles by blockIdx range ----------------
// role B: lit -> LT bf16x4 [29][NEP]: 234 * 8 = 1872 blocks
// role C: per-batch prep + WA pack  : 64 blocks (2 b each)
#define NB_B 1872
#define NB_C 64

__global__ __launch_bounds__(256) void prep_all(
    const int* __restrict__ e1_idx, const int* __restrict__ r_idx,
    const float* __restrict__ E, const float* __restrict__ R,
    const float* __restrict__ nf, const float* __restrict__ lit,
    const float* __restrict__ c, const float* __restrict__ var,
    float* __restrict__ ws)
{
    __shared__ float lwb[2][224];
    const int bid = blockIdx.x;
    const int t   = threadIdx.x;

    if (bid < NB_B) {                       // ---- lit -> bf16x4 [29][NEP] ----
        const int ebk = bid % 234;
        const int cq  = (bid / 234) * 4 + (t >> 6);   // 0..31
        const int e   = ebk * 64 + (t & 63);
        if (cq >= 29) return;
        uint2 o = make_uint2(0u, 0u);
        if (e < NE) {
            float4 L = *(const float4*)(lit + e*NL + 4*cq);
            o.x = bf16rne(L.x) | (bf16rne(L.y) << 16);
            o.y = bf16rne(L.z) | (bf16rne(L.w) << 16);
        }
        ((uint2*)(ws + OFF_LT))[cq*NEP + e] = o;
    } else {                                // ---- per-batch prep + WA pack ----
        const int cb  = bid - NB_B;         // 0..63
        const int sub = t >> 7;             // 0..1
        const int b   = cb*2 + sub;
        const int tt  = t & 127;
        const int e1 = e1_idx[b];
        const int r  = r_idx[b];
        if (tt < D2) {
            float e1r = E[e1*D + tt],      e1i = E[e1*D + D2 + tt];
            float rr  = R[r*D + tt],       ri  = R[r*D + D2 + tt];
            lwb[sub][tt]      = e1r*rr - e1i*ri;
            lwb[sub][D2 + tt] = e1r*ri + e1i*rr;
        }
        if (tt >= 100 && tt < 124) lwb[sub][100 + tt] = 0.f;   // d = 200..223
        if (tt < NL) {
            float a = lit[e1*NL + tt] - c[tt];
            float qq = -LOG2E / var[tt];
            (ws + OFF_UB)[b*NL + tt] = -2.0f * qq * a;
            (ws + OFF_FB)[b*NL + tt] = nf[r*NL + tt] * __builtin_amdgcn_exp2f(qq * a * a);
            if (b == 0) (ws + OFF_NQ)[tt] = qq;
        }
        __syncthreads();
        if (tt < 28) {
            const float* w8 = &lwb[sub][8*tt];
            uint4 o;
            o.x = bf16rne(w8[0]) | (bf16rne(w8[1]) << 16);
            o.y = bf16rne(w8[2]) | (bf16rne(w8[3]) << 16);
            o.z = bf16rne(w8[4]) | (bf16rne(w8[5]) << 16);
            o.w = bf16rne(w8[6]) | (bf16rne(w8[7]) << 16);
            ((uint4*)(ws + OFF_WA))[tt*128 + b] = o;
        }
    }
}

// ---------------- gemm: SL[b][e] = sum_d w[b][d]*E[e][d], bf16 MFMA ----------------
// One wave per nb e-tile; loops ALL 8 mb b-tiles (R19 structure). B-fragments
// converted from E on the fly: lanes at fixed kc read 16 rows x 128B contiguous
// -> full-line gather, E read exactly once chip-wide. No ET table.

__global__ __launch_bounds__(256) void gemm_kernel(
    const float* __restrict__ E, const uint4* __restrict__ wa,
    float* __restrict__ sl)
{
    const int nb = blockIdx.x * 4 + (threadIdx.x >> 6);  // 0..935 (e-tile)
    const int l  = threadIdx.x & 63;
    const int lane16 = l & 15;
    const int grp    = l >> 4;
    const int e  = nb*16 + lane16;
    const int er = min(e, NE - 1);       // clamp padded tail (rows NE..NEP-1)

    f32x4 acc[8];
#pragma unroll
    for (int mb = 0; mb < 8; ++mb) acc[mb] = {0.f, 0.f, 0.f, 0.f};

#pragma unroll
    for (int kc = 0; kc < 7; ++kc) {
        const int s = kc*4 + grp;        // 0..27 ; d = 8s..8s+7 (s=25..27 -> pad)
        uint4 o = make_uint4(0u, 0u, 0u, 0u);
        if (s < 25) {                    // d < 200
            float4 a4 = *(const float4*)(E + er*D + 8*s);
            float4 b4 = *(const float4*)(E + er*D + 8*s + 4);
            o.x = bf16rne(a4.x) | (bf16rne(a4.y) << 16);
            o.y = bf16rne(a4.z) | (bf16rne(a4.w) << 16);
            o.z = bf16rne(b4.x) | (bf16rne(b4.y) << 16);
            o.w = bf16rne(b4.z) | (bf16rne(b4.w) << 16);
        }
        bf16x8 bfrag = *(const bf16x8*)&o;
#pragma unroll
        for (int mb = 0; mb < 8; ++mb) {
            bf16x8 a = *(const bf16x8*)(wa + s*128 + mb*16 + lane16);
            acc[mb] = __builtin_amdgcn_mfma_f32_16x16x32_bf16(a, bfrag, acc[mb], 0, 0, 0);
        }
    }
#pragma unroll
    for (int mb = 0; mb < 8; ++mb) {
        const int brow = mb*16 + grp*4;
#pragma unroll
        for (int r = 0; r < 4; ++r)
            sl[(brow + r)*NEP + e] = acc[mb][r];
    }
}

// ---------------- score_n: lane = entity; scalar batch operands ----------------

#define SN_STEP(lv, cq) do {                                              \
    float L0 = BF2F_LO((lv).x), L1 = BF2F_HI((lv).x);                     \
    float L2 = BF2F_LO((lv).y), L3 = BF2F_HI((lv).y);                     \
    float4 q = *(const float4*)(nq + 4*(cq));                             \
    float g0 = (q.x*L0)*L0, g1 = (q.y*L1)*L1;                             \
    float g2 = (q.z*L2)*L2, g3 = (q.w*L3)*L3;                             \
    _Pragma("unroll")                                                     \
    for (int j = 0; j < EB; ++j) {                                        \
        float4 uj = *(const float4*)(ub + (b0+j)*NL + 4*(cq));            \
        float4 fj = *(const float4*)(fb + (b0+j)*NL + 4*(cq));            \
        acc[j] = fmaf(fj.x, __builtin_amdgcn_exp2f(fmaf(uj.x, L0, g0)), acc[j]); \
        acc[j] = fmaf(fj.y, __builtin_amdgcn_exp2f(fmaf(uj.y, L1, g1)), acc[j]); \
        acc[j] = fmaf(fj.z, __builtin_amdgcn_exp2f(fmaf(uj.z, L2, g2)), acc[j]); \
        acc[j] = fmaf(fj.w, __builtin_amdgcn_exp2f(fmaf(uj.w, L3, g3)), acc[j]); \
    }                                                                     \
} while (0)

__global__ __launch_bounds__(128) void score_kernel(
    const float* __restrict__ lt4, const float* __restrict__ sl,
    const float* __restrict__ ub,  const float* __restrict__ fb,
    const float* __restrict__ nq,  float* __restrict__ out)
{
    // grid = 3744 = 117 eblk * 32 bblk; partition e-range per XCD (lid&7)
    const int lid  = blockIdx.x;
    const int p    = (lid & 7) * 468 + (lid >> 3);
    const int eblk = p >> 5;            // 0..116
    const int bblk = p & 31;            // 0..31
    const int e    = eblk * 128 + threadIdx.x;
    const int b0   = bblk * EB;

    // ---- acc init from MFMA score_l ----
    float acc[EB];
#pragma unroll
    for (int j = 0; j < EB; ++j) acc[j] = sl[(b0+j)*NEP + e];

    const uint2* L4 = (const uint2*)lt4;

    // ---- score_n: 29 bf16x4 chunks, 4-deep rolling prefetch, no clamps ----
    {
        uint2 lv0 = L4[0*NEP + e];
        uint2 lv1 = L4[1*NEP + e];
        uint2 lv2 = L4[2*NEP + e];
        uint2 lv3 = L4[3*NEP + e];
        for (int cq0 = 0; cq0 < 24; cq0 += 4) {
            SN_STEP(lv0, cq0 + 0); lv0 = L4[(cq0 + 4)*NEP + e];
            SN_STEP(lv1, cq0 + 1); lv1 = L4[(cq0 + 5)*NEP + e];
            SN_STEP(lv2, cq0 + 2); lv2 = L4[(cq0 + 6)*NEP + e];
            SN_STEP(lv3, cq0 + 3); lv3 = L4[(cq0 + 7)*NEP + e];
        }
        // slots hold chunks 24..27; one extra load for 28
        SN_STEP(lv0, 24); lv0 = L4[28*NEP + e];
        SN_STEP(lv1, 25);
        SN_STEP(lv2, 26);
        SN_STEP(lv3, 27);
        SN_STEP(lv0, 28);
    }

    // ---- sigmoid + coalesced store ----
    if (e < NE) {
#pragma unroll
        for (int j = 0; j < EB; ++j) {
            float s = __builtin_amdgcn_rcpf(1.0f + __builtin_amdgcn_exp2f(acc[j] * -LOG2E));
            out[(b0+j)*NE + e] = s;
        }
    }
}

// ---------------- legacy fallback (ws too small) ----------------

#define ET  4
#define OFF_W   0
#define OFF_A   25600
#define OFF_WNF 40448
#define OFF_NQL 55296

__global__ __launch_bounds__(128) void prep_kernel_legacy(
    const int* __restrict__ e1_idx, const int* __restrict__ r_idx,
    const float* __restrict__ E, const float* __restrict__ R,
    const float* __restrict__ nf, const float* __restrict__ lit,
    const float* __restrict__ c, const float* __restrict__ var,
    float* __restrict__ ws)
{
    const int b = blockIdx.x;
    const int t = threadIdx.x;
    const int e1 = e1_idx[b];
    const int r  = r_idx[b];
    if (t < D2) {
        float e1r = E[e1*D + t], e1i = E[e1*D + D2 + t];
        float rr  = R[r*D + t],  ri  = R[r*D + D2 + t];
        ws[OFF_W + (t >> 2)*512        + (b << 2) + (t & 3)] = e1r*rr - e1i*ri;
        ws[OFF_W + ((t >> 2) + 25)*512 + (b << 2) + (t & 3)] = e1r*ri + e1i*rr;
    }
    if (t < NL) {
        ws[OFF_A   + (t >> 2)*512 + (b << 2) + (t & 3)] = lit[e1*NL + t] - c[t];
        ws[OFF_WNF + (t >> 2)*512 + (b << 2) + (t & 3)] = nf[r*NL + t];
        if (b == 0) ws[OFF_NQL + t] = -LOG2E / var[t];
    }
}

__global__ __launch_bounds__(128) void main_kernel_legacy(
    const float* __restrict__ E, const float* __restrict__ lit,
    const float* __restrict__ ws, float* __restrict__ out)
{
    const int b  = threadIdx.x;
    const int e0 = blockIdx.x * ET;
    const float4* w4   = (const float4*)(ws + OFF_W);
    const float4* a4   = (const float4*)(ws + OFF_A);
    const float4* wnf4 = (const float4*)(ws + OFF_WNF);
    const float*  nqv  = ws + OFF_NQL;
    int eidx[ET];
#pragma unroll
    for (int j = 0; j < ET; ++j) eidx[j] = min(e0 + j, NE - 1);
    float acc[ET];
#pragma unroll
    for (int j = 0; j < ET; ++j) acc[j] = 0.0f;
    for (int dc = 0; dc < D; dc += 4) {
        float4 wv = w4[(dc >> 2)*B + b];
#pragma unroll
        for (int j = 0; j < ET; ++j) {
            float4 ev = *(const float4*)(E + eidx[j]*D + dc);
            acc[j] = fmaf(wv.x, ev.x, acc[j]);
            acc[j] = fmaf(wv.y, ev.y, acc[j]);
            acc[j] = fmaf(wv.z, ev.z, acc[j]);
            acc[j] = fmaf(wv.w, ev.w, acc[j]);
        }
    }
    for (int lc = 0; lc < NL; lc += 4) {
        float4 av = a4[(lc >> 2)*B + b];
        float4 wv = wnf4[(lc >> 2)*B + b];
        float4 q  = *(const float4*)(nqv + lc);
#pragma unroll
        for (int j = 0; j < ET; ++j) {
            float4 lv = *(const float4*)(lit + eidx[j]*NL + lc);
            float t0 = av.x - lv.x, t1 = av.y - lv.y, t2 = av.z - lv.z, t3 = av.w - lv.w;
            acc[j] += wv.x * __builtin_amdgcn_exp2f(t0*t0*q.x);
            acc[j] += wv.y * __builtin_amdgcn_exp2f(t1*t1*q.y);
            acc[j] += wv.z * __builtin_amdgcn_exp2f(t2*t2*q.z);
            acc[j] += wv.w * __builtin_amdgcn_exp2f(t3*t3*q.w);
        }
    }
#pragma unroll
    for (int j = 0; j < ET; ++j) {
        float s = 1.0f / (1.0f + __builtin_amdgcn_exp2f(acc[j] * -LOG2E));
        int e = e0 + j;
        if (e < NE) out[b*NE + e] = s;
    }
}

// ---------------- launch ----------------

extern "C" void kernel_launch(void* const* d_in, const int* in_sizes, int n_in,
                              void* d_out, int out_size, void* d_ws, size_t ws_size,
                              hipStream_t stream) {
    const int*   e1_idx = (const int*)d_in[0];
    const int*   r_idx  = (const int*)d_in[1];
    const float* E      = (const float*)d_in[2];
    const float* R      = (const float*)d_in[3];
    const float* nf     = (const float*)d_in[4];
    const float* lit    = (const float*)d_in[5];
    const float* c      = (const float*)d_in[6];
    const float* var    = (const float*)d_in[7];
    float* out = (float*)d_out;
    float* ws  = (float*)d_ws;

    if (ws_size >= WS_NEEDED) {
        prep_all<<<NB_B + NB_C, 256, 0, stream>>>(
            e1_idx, r_idx, E, R, nf, lit, c, var, ws);
        gemm_kernel<<<234, 256, 0, stream>>>(
            E, (const uint4*)(ws + OFF_WA), ws + OFF_SL);
        score_kernel<<<3744, 128, 0, stream>>>(
            ws + OFF_LT, ws + OFF_SL, ws + OFF_UB, ws + OFF_FB, ws + OFF_NQ, out);
    } else {
        prep_kernel_legacy<<<B, 128, 0, stream>>>(e1_idx, r_idx, E, R, nf, lit, c, var, ws);
        main_kernel_legacy<<<(NE + ET - 1)/ET, B, 0, stream>>>(E, lit, ws, out);
    }
}